// Round 5
// baseline (298.943 us; speedup 1.0000x reference)
//
#include <hip/hip_runtime.h>

// LatentTexture: quantize-STE (8b hi / 4b lo) + align_corners bilinear sample.
// Two-pass through d_ws:
//   pass 1: streaming quantize + channel-last u8 repack (1 px/thread, plain
//           cached loads -- source is L3-resident from the harness restore)
//   pass 2: QUAD-per-sample scattered sample: lane t in [0,4) fetches bilinear
//           tap t (one uint4 hi + one dword lo), weights it, quad-butterfly
//           (__shfl_xor 1,2) reduces, lane t stores float4 -> fully coalesced.
// History: R1 direct 311us; R2 4px-repack 308.6; R4 1px+NT 292.4.
// dur_us carries ~185us of in-stream harness restore/poison overhead.

#define NSAMP   131072
#define HI_W    2048
#define LO_W    512
#define HI_PIX  (HI_W * HI_W)            // 4,194,304
#define LO_PIX  (LO_W * LO_W)            // 262,144
#define HI_PX_BLOCKS (HI_PIX / 256)      // 16384  (1 px/thread)
#define LO_PX_BLOCKS (LO_PIX / 256)      // 1024
#define WS_NEED ((size_t)HI_PIX * 16 + (size_t)LO_PIX * 4)

typedef float fx4 __attribute__((ext_vector_type(4)));   // NT-store-compatible

__device__ __forceinline__ unsigned int quant_u(float v, float qmax) {
    return (unsigned int)rintf(fminf(fmaxf(v, 0.0f), 1.0f) * qmax);
}

// ---- Pass 1: quantize + transpose to channel-last u8, 1 px/thread ----------
__global__ __launch_bounds__(256)
void quant_pack_kernel(const float* __restrict__ hi,     // [12][HI_PIX]
                       const float* __restrict__ lo,     // [4][LO_PIX]
                       uint4* __restrict__ hiT,          // [HI_PIX]
                       unsigned int* __restrict__ loT)   // [LO_PIX]
{
    const int b = blockIdx.x;
    if (b < HI_PX_BLOCKS) {
        const int p = b * 256 + threadIdx.x;
        unsigned int w0 = 0, w1 = 0, w2 = 0;
        #pragma unroll
        for (int c = 0; c < 4; ++c)
            w0 |= quant_u(hi[(size_t)c * HI_PIX + p], 255.0f) << (c * 8);
        #pragma unroll
        for (int c = 4; c < 8; ++c)
            w1 |= quant_u(hi[(size_t)c * HI_PIX + p], 255.0f) << ((c - 4) * 8);
        #pragma unroll
        for (int c = 8; c < 12; ++c)
            w2 |= quant_u(hi[(size_t)c * HI_PIX + p], 255.0f) << ((c - 8) * 8);
        hiT[p] = make_uint4(w0, w1, w2, 0u);             // wave: 1KB contiguous
    } else {
        const int p = (b - HI_PX_BLOCKS) * 256 + threadIdx.x;
        unsigned int w = 0;
        #pragma unroll
        for (int c = 0; c < 4; ++c)
            w |= quant_u(lo[(size_t)c * LO_PIX + p], 15.0f) << (c * 8);
        loT[p] = w;
    }
}

// ---- Pass 2: bilinear sample, 4 lanes per sample (lane = tap) --------------
__global__ __launch_bounds__(256)
void sample_kernel(const float2* __restrict__ uv,
                   const uint4* __restrict__ hiT,
                   const unsigned int* __restrict__ loT,
                   fx4* __restrict__ out)
{
    const int tid = blockIdx.x * 256 + threadIdx.x;
    const int s = tid >> 2;        // sample
    const int t = tid & 3;         // tap: t&1 -> x side, t>>1 -> y side
    const int tx = t & 1, ty = t >> 1;

    const float2 p = uv[s];        // 4-way broadcast within quad

    float r[16];

    // ---------- hi (2048x2048, 12 ch) ----------
    {
        const float gx = p.x * 2.0f - 1.0f, gy = p.y * 2.0f - 1.0f;
        const float ix = (gx + 1.0f) * 0.5f * (float)(HI_W - 1);
        const float iy = (gy + 1.0f) * 0.5f * (float)(HI_W - 1);
        const float ix0f = floorf(ix), iy0f = floorf(iy);
        const float wx = ix - ix0f, wy = iy - iy0f;
        int ix0 = min(max((int)ix0f, 0), HI_W - 1);
        int iy0 = min(max((int)iy0f, 0), HI_W - 1);
        const int ix1 = min(ix0 + 1, HI_W - 1);
        const int iy1 = min(iy0 + 1, HI_W - 1);
        const int xs = tx ? ix1 : ix0;
        const int ys = ty ? iy1 : iy0;
        const float wgt = (tx ? wx : 1.0f - wx) * (ty ? wy : 1.0f - wy);
        const uint4 a = hiT[(size_t)ys * HI_W + xs];     // ONE scattered 16B load
        const unsigned int w[3] = {a.x, a.y, a.z};
        #pragma unroll
        for (int c = 0; c < 12; ++c)
            r[c] = (float)((w[c >> 2] >> ((c & 3) * 8)) & 0xff) * wgt;
    }

    // ---------- lo (512x512, 4 ch) ----------
    {
        const float gx = p.x * 2.0f - 1.0f, gy = p.y * 2.0f - 1.0f;
        const float ix = (gx + 1.0f) * 0.5f * (float)(LO_W - 1);
        const float iy = (gy + 1.0f) * 0.5f * (float)(LO_W - 1);
        const float ix0f = floorf(ix), iy0f = floorf(iy);
        const float wx = ix - ix0f, wy = iy - iy0f;
        int ix0 = min(max((int)ix0f, 0), LO_W - 1);
        int iy0 = min(max((int)iy0f, 0), LO_W - 1);
        const int ix1 = min(ix0 + 1, LO_W - 1);
        const int iy1 = min(iy0 + 1, LO_W - 1);
        const int xs = tx ? ix1 : ix0;
        const int ys = ty ? iy1 : iy0;
        const float wgt = (tx ? wx : 1.0f - wx) * (ty ? wy : 1.0f - wy);
        const unsigned int l = loT[ys * LO_W + xs];      // ONE scattered 4B load
        #pragma unroll
        for (int c = 0; c < 4; ++c)
            r[12 + c] = (float)((l >> (c * 8)) & 0xff) * wgt;
    }

    // quad butterfly: sum the 4 taps (xor 1, then xor 2 -> DPP, cheap)
    #pragma unroll
    for (int j = 0; j < 16; ++j) {
        r[j] += __shfl_xor(r[j], 1);
        r[j] += __shfl_xor(r[j], 2);
    }

    // lane t stores channels [4t, 4t+4): consecutive lanes -> consecutive 16B
    const float sc = (t == 3) ? (1.0f / 15.0f) : (1.0f / 255.0f);
    const int k = 4 * t;
    fx4 v = { r[k] * sc, r[k + 1] * sc, r[k + 2] * sc, r[k + 3] * sc };
    __builtin_nontemporal_store(v, &out[tid]);           // out[s*4 + t]
}

// ---- Fallback (round-1 direct kernel) if ws is unexpectedly small ----------
__global__ __launch_bounds__(256)
void direct_kernel(const float2* __restrict__ uv,
                   const float*  __restrict__ hi,
                   const float*  __restrict__ lo,
                   float*        __restrict__ out)
{
    const int tid = blockIdx.x * 256 + threadIdx.x;
    const int s = tid >> 4, c = tid & 15;
    const float2 p = uv[s];
    const float* tex; int W; float qmax, rq;
    if (c < 12) { tex = hi + (size_t)c * HI_PIX; W = HI_W; qmax = 255.0f; rq = 1.0f/255.0f; }
    else        { tex = lo + (size_t)(c-12) * LO_PIX; W = LO_W; qmax = 15.0f; rq = 1.0f/15.0f; }
    const float gx = p.x * 2.0f - 1.0f, gy = p.y * 2.0f - 1.0f;
    const float ix = (gx + 1.0f) * 0.5f * (float)(W - 1);
    const float iy = (gy + 1.0f) * 0.5f * (float)(W - 1);
    const float ix0f = floorf(ix), iy0f = floorf(iy);
    const float wx = ix - ix0f, wy = iy - iy0f;
    int ix0 = min(max((int)ix0f, 0), W - 1);
    int iy0 = min(max((int)iy0f, 0), W - 1);
    const int ix1 = min(ix0 + 1, W - 1), iy1 = min(iy0 + 1, W - 1);
    const float* r0 = tex + (size_t)iy0 * W;
    const float* r1 = tex + (size_t)iy1 * W;
    float v00 = rintf(fminf(fmaxf(r0[ix0],0.f),1.f)*qmax)*rq;
    float v01 = rintf(fminf(fmaxf(r0[ix1],0.f),1.f)*qmax)*rq;
    float v10 = rintf(fminf(fmaxf(r1[ix0],0.f),1.f)*qmax)*rq;
    float v11 = rintf(fminf(fmaxf(r1[ix1],0.f),1.f)*qmax)*rq;
    out[(size_t)s*16 + c] = v00*(1.f-wy)*(1.f-wx) + v01*(1.f-wy)*wx
                          + v10*wy*(1.f-wx)       + v11*wy*wx;
}

extern "C" void kernel_launch(void* const* d_in, const int* in_sizes, int n_in,
                              void* d_out, int out_size, void* d_ws, size_t ws_size,
                              hipStream_t stream) {
    const float2* uv = (const float2*)d_in[0];
    const float*  hi = (const float*)d_in[1];
    const float*  lo = (const float*)d_in[2];
    float* out = (float*)d_out;

    if (ws_size < WS_NEED) {
        direct_kernel<<<(NSAMP * 16) / 256, 256, 0, stream>>>(uv, hi, lo, out);
        return;
    }

    uint4* hiT = (uint4*)d_ws;                                   // 64 MiB
    unsigned int* loT = (unsigned int*)((char*)d_ws + (size_t)HI_PIX * 16);  // 1 MiB

    quant_pack_kernel<<<HI_PX_BLOCKS + LO_PX_BLOCKS, 256, 0, stream>>>(hi, lo, hiT, loT);
    sample_kernel<<<(NSAMP * 4) / 256, 256, 0, stream>>>(uv, hiT, loT, (fx4*)out);
}

// Round 6
// 291.224 us; speedup vs baseline: 1.0265x; 1.0265x over previous
//
#include <hip/hip_runtime.h>

// LatentTexture: quantize-STE (8b hi / 4b lo) + align_corners bilinear sample.
// Two-pass through d_ws:
//   pass 1: streaming quantize + channel-last u8 repack (1 px/thread, NT
//           loads on touch-once f32 input, coalesced uint4 store)  [R4 exact]
//   pass 2: 2 lanes/sample split by y-row: each lane loads its row's two
//           adjacent texels (x0,x1 same cache line), x-blends in-lane,
//           one __shfl_xor(.,1)/channel y-blends, lane t stores ch[8t..8t+8)
//           -> consecutive 32B segments, 2x waves vs R4's 1 thread/sample.
// History: R1 direct 311; R2 4px-repack 308.6; R4 1px+NT 292.4 (best);
//          R5 quad-split+no-NT 298.9 (VALU x4 in pass-2 regressed).
// dur_us carries ~185us of in-stream harness restore/poison overhead.

#define NSAMP   131072
#define HI_W    2048
#define LO_W    512
#define HI_PIX  (HI_W * HI_W)            // 4,194,304
#define LO_PIX  (LO_W * LO_W)            // 262,144
#define HI_PX_BLOCKS (HI_PIX / 256)      // 16384  (1 px/thread)
#define LO_PX_BLOCKS (LO_PIX / 256)      // 1024
#define WS_NEED ((size_t)HI_PIX * 16 + (size_t)LO_PIX * 4)

typedef float fx4 __attribute__((ext_vector_type(4)));   // NT-store-compatible

__device__ __forceinline__ unsigned int quant_u(float v, float qmax) {
    return (unsigned int)rintf(fminf(fmaxf(v, 0.0f), 1.0f) * qmax);
}

// ---- Pass 1: quantize + transpose to channel-last u8, 1 px/thread ----------
__global__ __launch_bounds__(256)
void quant_pack_kernel(const float* __restrict__ hi,     // [12][HI_PIX]
                       const float* __restrict__ lo,     // [4][LO_PIX]
                       uint4* __restrict__ hiT,          // [HI_PIX]
                       unsigned int* __restrict__ loT)   // [LO_PIX]
{
    const int b = blockIdx.x;
    if (b < HI_PX_BLOCKS) {
        const int p = b * 256 + threadIdx.x;
        unsigned int w0 = 0, w1 = 0, w2 = 0;
        #pragma unroll
        for (int c = 0; c < 4; ++c)
            w0 |= quant_u(__builtin_nontemporal_load(hi + (size_t)c * HI_PIX + p), 255.0f) << (c * 8);
        #pragma unroll
        for (int c = 4; c < 8; ++c)
            w1 |= quant_u(__builtin_nontemporal_load(hi + (size_t)c * HI_PIX + p), 255.0f) << ((c - 4) * 8);
        #pragma unroll
        for (int c = 8; c < 12; ++c)
            w2 |= quant_u(__builtin_nontemporal_load(hi + (size_t)c * HI_PIX + p), 255.0f) << ((c - 8) * 8);
        hiT[p] = make_uint4(w0, w1, w2, 0u);             // wave: 1KB contiguous
    } else {
        const int p = (b - HI_PX_BLOCKS) * 256 + threadIdx.x;
        unsigned int w = 0;
        #pragma unroll
        for (int c = 0; c < 4; ++c)
            w |= quant_u(__builtin_nontemporal_load(lo + (size_t)c * LO_PIX + p), 15.0f) << (c * 8);
        loT[p] = w;
    }
}

// ---- Pass 2: bilinear sample, 2 lanes per sample (lane = y-row) ------------
__global__ __launch_bounds__(256)
void sample_kernel(const float2* __restrict__ uv,
                   const uint4* __restrict__ hiT,
                   const unsigned int* __restrict__ loT,
                   fx4* __restrict__ out)
{
    const int tid = blockIdx.x * 256 + threadIdx.x;
    const int s = tid >> 1;        // sample
    const int t = tid & 1;         // y-tap (0 -> y0 row, 1 -> y1 row)

    const float2 p = uv[s];        // pair-broadcast

    // ---------- hi coords (2048x2048) ----------
    const float gxh = p.x * 2.0f - 1.0f, gyh = p.y * 2.0f - 1.0f;
    const float ixh = (gxh + 1.0f) * 0.5f * (float)(HI_W - 1);
    const float iyh = (gyh + 1.0f) * 0.5f * (float)(HI_W - 1);
    const float ixh0f = floorf(ixh), iyh0f = floorf(iyh);
    const float wxh = ixh - ixh0f, wyh = iyh - iyh0f;
    int ixh0 = min(max((int)ixh0f, 0), HI_W - 1);
    int iyh0 = min(max((int)iyh0f, 0), HI_W - 1);
    const int ixh1 = min(ixh0 + 1, HI_W - 1);
    const int iyh1 = min(iyh0 + 1, HI_W - 1);
    const int ysh = t ? iyh1 : iyh0;
    const float wyf_h = t ? wyh : 1.0f - wyh;

    // ---------- lo coords (512x512) ----------
    const float ixl = (gxh + 1.0f) * 0.5f * (float)(LO_W - 1);
    const float iyl = (gyh + 1.0f) * 0.5f * (float)(LO_W - 1);
    const float ixl0f = floorf(ixl), iyl0f = floorf(iyl);
    const float wxl = ixl - ixl0f, wyl = iyl - iyl0f;
    int ixl0 = min(max((int)ixl0f, 0), LO_W - 1);
    int iyl0 = min(max((int)iyl0f, 0), LO_W - 1);
    const int ixl1 = min(ixl0 + 1, LO_W - 1);
    const int iyl1 = min(iyl0 + 1, LO_W - 1);
    const int ysl = t ? iyl1 : iyl0;
    const float wyf_l = t ? wyl : 1.0f - wyl;

    // issue all 4 scattered loads up front (x-pairs are line-adjacent)
    const uint4 a0 = hiT[(size_t)ysh * HI_W + ixh0];
    const uint4 a1 = hiT[(size_t)ysh * HI_W + ixh1];
    const unsigned int l0 = loT[ysl * LO_W + ixl0];
    const unsigned int l1 = loT[ysl * LO_W + ixl1];

    float r[16];
    {
        const unsigned int u0[3] = {a0.x, a0.y, a0.z};
        const unsigned int u1[3] = {a1.x, a1.y, a1.z};
        const float omwx = 1.0f - wxh;
        #pragma unroll
        for (int c = 0; c < 12; ++c) {
            const int w = c >> 2, sh = (c & 3) * 8;
            const float v0 = (float)((u0[w] >> sh) & 0xff);
            const float v1 = (float)((u1[w] >> sh) & 0xff);
            r[c] = wyf_h * (v0 * omwx + v1 * wxh);
        }
    }
    {
        const float omwx = 1.0f - wxl;
        #pragma unroll
        for (int c = 0; c < 4; ++c) {
            const int sh = c * 8;
            const float v0 = (float)((l0 >> sh) & 0xff);
            const float v1 = (float)((l1 >> sh) & 0xff);
            r[12 + c] = wyf_l * (v0 * omwx + v1 * wxl);
        }
    }

    // y-blend across the lane pair: one shuffle per channel
    #pragma unroll
    for (int j = 0; j < 16; ++j)
        r[j] += __shfl_xor(r[j], 1);

    // lane t stores channels [8t, 8t+8): two consecutive fx4 -> coalesced 32B
    const int base = 8 * t;
    fx4 v0, v1;
    #pragma unroll
    for (int j = 0; j < 4; ++j) {
        const int c0 = base + j, c1 = base + 4 + j;
        v0[j] = r[c0] * ((c0 < 12) ? (1.0f / 255.0f) : (1.0f / 15.0f));
        v1[j] = r[c1] * ((c1 < 12) ? (1.0f / 255.0f) : (1.0f / 15.0f));
    }
    __builtin_nontemporal_store(v0, &out[(size_t)tid * 2]);
    __builtin_nontemporal_store(v1, &out[(size_t)tid * 2 + 1]);
}

// ---- Fallback (round-1 direct kernel) if ws is unexpectedly small ----------
__global__ __launch_bounds__(256)
void direct_kernel(const float2* __restrict__ uv,
                   const float*  __restrict__ hi,
                   const float*  __restrict__ lo,
                   float*        __restrict__ out)
{
    const int tid = blockIdx.x * 256 + threadIdx.x;
    const int s = tid >> 4, c = tid & 15;
    const float2 p = uv[s];
    const float* tex; int W; float qmax, rq;
    if (c < 12) { tex = hi + (size_t)c * HI_PIX; W = HI_W; qmax = 255.0f; rq = 1.0f/255.0f; }
    else        { tex = lo + (size_t)(c-12) * LO_PIX; W = LO_W; qmax = 15.0f; rq = 1.0f/15.0f; }
    const float gx = p.x * 2.0f - 1.0f, gy = p.y * 2.0f - 1.0f;
    const float ix = (gx + 1.0f) * 0.5f * (float)(W - 1);
    const float iy = (gy + 1.0f) * 0.5f * (float)(W - 1);
    const float ix0f = floorf(ix), iy0f = floorf(iy);
    const float wx = ix - ix0f, wy = iy - iy0f;
    int ix0 = min(max((int)ix0f, 0), W - 1);
    int iy0 = min(max((int)iy0f, 0), W - 1);
    const int ix1 = min(ix0 + 1, W - 1), iy1 = min(iy0 + 1, W - 1);
    const float* r0 = tex + (size_t)iy0 * W;
    const float* r1 = tex + (size_t)iy1 * W;
    float v00 = rintf(fminf(fmaxf(r0[ix0],0.f),1.f)*qmax)*rq;
    float v01 = rintf(fminf(fmaxf(r0[ix1],0.f),1.f)*qmax)*rq;
    float v10 = rintf(fminf(fmaxf(r1[ix0],0.f),1.f)*qmax)*rq;
    float v11 = rintf(fminf(fmaxf(r1[ix1],0.f),1.f)*qmax)*rq;
    out[(size_t)s*16 + c] = v00*(1.f-wy)*(1.f-wx) + v01*(1.f-wy)*wx
                          + v10*wy*(1.f-wx)       + v11*wy*wx;
}

extern "C" void kernel_launch(void* const* d_in, const int* in_sizes, int n_in,
                              void* d_out, int out_size, void* d_ws, size_t ws_size,
                              hipStream_t stream) {
    const float2* uv = (const float2*)d_in[0];
    const float*  hi = (const float*)d_in[1];
    const float*  lo = (const float*)d_in[2];
    float* out = (float*)d_out;

    if (ws_size < WS_NEED) {
        direct_kernel<<<(NSAMP * 16) / 256, 256, 0, stream>>>(uv, hi, lo, out);
        return;
    }

    uint4* hiT = (uint4*)d_ws;                                   // 64 MiB
    unsigned int* loT = (unsigned int*)((char*)d_ws + (size_t)HI_PIX * 16);  // 1 MiB

    quant_pack_kernel<<<HI_PX_BLOCKS + LO_PX_BLOCKS, 256, 0, stream>>>(hi, lo, hiT, loT);
    sample_kernel<<<(NSAMP * 2) / 256, 256, 0, stream>>>(uv, hiT, loT, (fx4*)out);
}